// Round 1
// baseline (175.134 us; speedup 1.0000x reference)
//
#include <hip/hip_runtime.h>

// Problem constants (from reference)
constexpr int B   = 4;
constexpr int CF  = 3;    // feat channels
constexpr int CM  = 21;   // mask channels
constexpr int H   = 128;
constexpr int W   = 128;
constexpr int KS  = 7;
constexpr int PAD = 3;
constexpr int CENTER = (KS * KS) / 2;  // 24
constexpr int NNB = KS * KS - 1;       // 48 neighbors
constexpr int NUM_ITER = 10;

constexpr int TILE = 16;
constexpr int TH   = TILE + 2 * PAD;   // 22 (tile + halo)
constexpr int TS   = 24;               // LDS row stride, padded: ty*24 % 32 = {0,24,16,8} -> exactly 2-way aliasing (free)
constexpr int CPB  = 7;                // mask channels per block (21 = 3 groups)

// ---------------------------------------------------------------------------
// Kernel 1: per-pixel 48-way softmax affinity from feats
// aff layout: aff[((b*48 + n)*H + h)*W + w]  (n-major planes, coalesced in w)
// ---------------------------------------------------------------------------
__global__ __launch_bounds__(256) void aff_kernel(const float* __restrict__ feats,
                                                  float* __restrict__ aff) {
    __shared__ float tile[CF][TH][TS];
    const int tx = threadIdx.x, ty = threadIdx.y;
    const int bx = blockIdx.x * TILE, by = blockIdx.y * TILE;
    const int b  = blockIdx.z;
    const int tid = ty * TILE + tx;

    // Stage 22x22 halo tile for each of the 3 feat channels (edge-clamped)
    for (int c = 0; c < CF; ++c) {
        const float* src = feats + (size_t)(b * CF + c) * H * W;
        for (int idx = tid; idx < TH * TH; idx += 256) {
            const int r  = idx / TH, cc = idx - r * TH;
            const int gh = min(max(by + r  - PAD, 0), H - 1);
            const int gw = min(max(bx + cc - PAD, 0), W - 1);
            tile[c][r][cc] = src[gh * W + gw];
        }
    }
    __syncthreads();

    // Per-channel neighbor stats (two-pass mean/var, ddof=1) matching jnp.std
    float q[CF], inv[CF];
    #pragma unroll
    for (int c = 0; c < CF; ++c) {
        q[c] = tile[c][ty + PAD][tx + PAD];
        float s = 0.f;
        #pragma unroll
        for (int i = 0; i < KS; ++i)
            #pragma unroll
            for (int j = 0; j < KS; ++j) {
                if (i == PAD && j == PAD) continue;
                s += tile[c][ty + i][tx + j];
            }
        const float mean = s * (1.0f / NNB);
        float v = 0.f;
        #pragma unroll
        for (int i = 0; i < KS; ++i)
            #pragma unroll
            for (int j = 0; j < KS; ++j) {
                if (i == PAD && j == PAD) continue;
                const float d = tile[c][ty + i][tx + j] - mean;
                v += d * d;
            }
        const float sd = sqrtf(v * (1.0f / (NNB - 1)));
        inv[c] = 1.0f / (1e-8f + 0.1f * sd);
    }

    // Affinity + softmax over the 48 neighbors (all indices compile-time after unroll)
    float a[NNB];
    float mx = -1e30f;
    #pragma unroll
    for (int i = 0; i < KS; ++i)
        #pragma unroll
        for (int j = 0; j < KS; ++j) {
            const int nn = i * KS + j;
            if (nn == CENTER) continue;
            const int n = (nn < CENTER) ? nn : nn - 1;
            float t = 0.f;
            #pragma unroll
            for (int c = 0; c < CF; ++c)
                t += fabsf(tile[c][ty + i][tx + j] - q[c]) * inv[c];
            a[n] = -t * (1.0f / CF);
            mx = fmaxf(mx, a[n]);
        }
    float ssum = 0.f;
    #pragma unroll
    for (int n = 0; n < NNB; ++n) { a[n] = __expf(a[n] - mx); ssum += a[n]; }
    const float rs = 1.0f / ssum;

    const int h = by + ty, w = bx + tx;
    #pragma unroll
    for (int n = 0; n < NNB; ++n)
        aff[(((size_t)b * NNB + n) * H + h) * W + w] = a[n] * rs;
}

// ---------------------------------------------------------------------------
// Kernel 2: one propagation iteration. Each block: one 16x16 tile, 7 channels.
// aff weights live in 48 registers/thread; mask plane staged per channel in LDS.
// ---------------------------------------------------------------------------
__global__ __launch_bounds__(256) void iter_kernel(const float* __restrict__ mi,
                                                   const float* __restrict__ aff,
                                                   float* __restrict__ mo) {
    __shared__ float tile[TH][TS];
    const int tx = threadIdx.x, ty = threadIdx.y;
    const int bx = blockIdx.x * TILE, by = blockIdx.y * TILE;
    const int b  = blockIdx.z / (CM / CPB);
    const int c0 = (blockIdx.z % (CM / CPB)) * CPB;
    const int tid = ty * TILE + tx;
    const int h = by + ty, w = bx + tx;

    float a[NNB];
    #pragma unroll
    for (int n = 0; n < NNB; ++n)
        a[n] = aff[(((size_t)b * NNB + n) * H + h) * W + w];

    for (int c = c0; c < c0 + CPB; ++c) {
        const float* src = mi + (size_t)(b * CM + c) * H * W;
        __syncthreads();   // previous channel's tile no longer in use
        for (int idx = tid; idx < TH * TH; idx += 256) {
            const int r  = idx / TH, cc = idx - r * TH;
            const int gh = min(max(by + r  - PAD, 0), H - 1);
            const int gw = min(max(bx + cc - PAD, 0), W - 1);
            tile[r][cc] = src[gh * W + gw];
        }
        __syncthreads();
        float s = 0.f;
        #pragma unroll
        for (int i = 0; i < KS; ++i)
            #pragma unroll
            for (int j = 0; j < KS; ++j) {
                const int nn = i * KS + j;
                if (nn == CENTER) continue;
                const int n = (nn < CENTER) ? nn : nn - 1;
                s += a[n] * tile[ty + i][tx + j];
            }
        mo[((size_t)(b * CM + c) * H + h) * W + w] = s;
    }
}

// ---------------------------------------------------------------------------
extern "C" void kernel_launch(void* const* d_in, const int* in_sizes, int n_in,
                              void* d_out, int out_size, void* d_ws, size_t ws_size,
                              hipStream_t stream) {
    const float* feats = (const float*)d_in[0];
    const float* mask  = (const float*)d_in[1];
    float* out = (float*)d_out;

    float* aff = (float*)d_ws;                                   // 4*48*128*128*4 = 12.58 MB
    float* tmp = (float*)((char*)d_ws +
                          (size_t)B * NNB * H * W * sizeof(float)); // 4*21*128*128*4 = 5.5 MB

    dim3 blk(TILE, TILE);
    dim3 grid_aff(W / TILE, H / TILE, B);
    aff_kernel<<<grid_aff, blk, 0, stream>>>(feats, aff);

    dim3 grid_it(W / TILE, H / TILE, B * (CM / CPB));
    const float* src = mask;
    for (int t = 1; t <= NUM_ITER; ++t) {
        float* dst = (t & 1) ? tmp : out;   // iter 10 (even) lands in d_out
        iter_kernel<<<grid_it, blk, 0, stream>>>(src, aff, dst);
        src = dst;
    }
}